// Round 15
// baseline (117.182 us; speedup 1.0000x reference)
//
#include <hip/hip_runtime.h>

#define N_ATOMS 50000
#define N_BONDS 100000
#define BATCH   16
#define N3      150000   // N_ATOMS*3
#define BK      32       // bucket capacity per atom (Poisson(4): P(deg>32) ~ 1e-15)

// ---- fast-path workspace layout (4-byte element offsets) ----
#define X_OFF    0            // 4096 floats
#define MC_OFF   4096         // 16 floats (M 9, c 3)
#define CNT_OFF  4112         // 50000 ints (4112*4 % 16 == 0)
#define BKT_OFF  54112        // 50000*32 = 1,600,000 ints
#define HA_OFF   1654112      // 2,400,000 floats
#define HB_OFF   4054112      // 2,400,000 floats
#define WS_FAST_BYTES ((size_t)(HB_OFF + 2400000) * 4)   // ~25.8 MB

// ---- fallback layout ----
#define DEGF_OFF 4112         // 50000 floats
#define HT_OFF   54144        // 2,400,000 floats
#define NB_OFF   2454144      // 2,400,000 floats (optional in ws)

typedef __bf16 bf16x8 __attribute__((ext_vector_type(8)));
typedef float  f32x4  __attribute__((ext_vector_type(4)));

// ================= shared device helpers =================

// tiny MLP for batch b; all 256 threads of the block participate.
__device__ __forceinline__ void mlp_block(int b, int j,
    const float* __restrict__ alpha,
    const float* __restrict__ w_in, const float* __restrict__ b_in,
    const float* __restrict__ w1a, const float* __restrict__ b1a,
    const float* __restrict__ w1b, const float* __restrict__ b1b,
    const float* __restrict__ w2a, const float* __restrict__ b2a,
    const float* __restrict__ w2b, const float* __restrict__ b2b,
    float* xs, float* ts, float* __restrict__ x_out)
{
    float v = fmaxf(w_in[j] * alpha[b] + b_in[j], 0.f);
    xs[j] = v;
    __syncthreads();

    float acc = b1a[j];
    const float4* wr = reinterpret_cast<const float4*>(w1a + j * 256);
    #pragma unroll 8
    for (int k4 = 0; k4 < 64; ++k4) {
        float4 w = wr[k4];
        acc += w.x * xs[4*k4] + w.y * xs[4*k4+1] + w.z * xs[4*k4+2] + w.w * xs[4*k4+3];
    }
    ts[j] = fmaxf(acc, 0.f);
    __syncthreads();

    acc = b1b[j] + xs[j];
    wr = reinterpret_cast<const float4*>(w1b + j * 256);
    #pragma unroll 8
    for (int k4 = 0; k4 < 64; ++k4) {
        float4 w = wr[k4];
        acc += w.x * ts[4*k4] + w.y * ts[4*k4+1] + w.z * ts[4*k4+2] + w.w * ts[4*k4+3];
    }
    v = fmaxf(acc, 0.f);
    __syncthreads();
    xs[j] = v;
    __syncthreads();

    acc = b2a[j];
    wr = reinterpret_cast<const float4*>(w2a + j * 256);
    #pragma unroll 8
    for (int k4 = 0; k4 < 64; ++k4) {
        float4 w = wr[k4];
        acc += w.x * xs[4*k4] + w.y * xs[4*k4+1] + w.z * xs[4*k4+2] + w.w * xs[4*k4+3];
    }
    ts[j] = fmaxf(acc, 0.f);
    __syncthreads();

    acc = b2b[j] + xs[j];
    wr = reinterpret_cast<const float4*>(w2b + j * 256);
    #pragma unroll 8
    for (int k4 = 0; k4 < 64; ++k4) {
        float4 w = wr[k4];
        acc += w.x * ts[4*k4] + w.y * ts[4*k4+1] + w.z * ts[4*k4+2] + w.w * ts[4*k4+3];
    }
    x_out[b * 256 + j] = fmaxf(acc, 0.f);
}

// ================= K1: prep (MLP + mc + transpose + cnt-zero) =================
// Transpose keeps R7's proven mapping: coalesced WRITES to h, 12B scattered
// reads of pos (L2-absorbed). R8's read-coalesced variant regressed 15-20us.
struct PrepParams {
    const float *alpha, *pos;
    const float *w_in, *b_in, *w1a, *b1a, *w1b, *b1b, *w2a, *b2a, *w2b, *b2b;
    const float *msg_w, *msg_b, *upd_w, *upd_b;
    float *x, *mc;
    int *cnt;
    float *hA;
};

__global__ __launch_bounds__(256) void prep_kernel(PrepParams p)
{
    __shared__ float smem[512];
    const int bid = blockIdx.x, tid = threadIdx.x;
    const int nb = gridDim.x;

    if (bid < 16) {
        mlp_block(bid, tid, p.alpha, p.w_in, p.b_in,
                  p.w1a, p.b1a, p.w1b, p.b1b, p.w2a, p.b2a, p.w2b, p.b2b,
                  smem, smem + 256, p.x);
    } else if (bid == 16) {
        if (tid < 9) {
            int d = tid / 3, dp = tid % 3;
            float s = 0.f;
            for (int k = 0; k < 128; ++k) s += p.upd_w[d*128 + k] * p.msg_w[k*3 + dp];
            p.mc[tid] = s;
        } else if (tid < 12) {
            int d = tid - 9;
            float s = p.upd_b[d];
            for (int k = 0; k < 128; ++k) s += p.upd_w[d*128 + k] * p.msg_b[k];
            p.mc[9 + d] = s;
        }
    } else {
        const int i0 = (bid - 17) * 256 + tid;
        const int st = (nb - 17) * 256;
        if (i0 < N_ATOMS / 4)
            ((int4*)p.cnt)[i0] = make_int4(0, 0, 0, 0);
        for (int i = i0; i < N_ATOMS * 48; i += st) {
            int n = i / 48, c = i - n * 48;
            int b = c / 3, d = c - b * 3;
            p.hA[i] = p.pos[(b * N_ATOMS + n) * 3 + d];
        }
    }
}

// ================= K2: bucket fill (count + adjacency in one pass) =================
__global__ void fill_kernel(const int* __restrict__ bonds, int* __restrict__ cnt,
                            int* __restrict__ bucket)
{
    int e = blockIdx.x * blockDim.x + threadIdx.x;
    if (e >= N_BONDS) return;
    int a = bonds[2*e], b = bonds[2*e + 1];
    int sa = atomicAdd(cnt + a, 1);
    if (sa < BK) bucket[a * BK + sa] = b;
    int sb = atomicAdd(cnt + b, 1);
    if (sb < BK) bucket[b * BK + sb] = a;
}

// ============ K3/K4: bucket gather + mean + affine + residual ============
__global__ void gather_kernel(const int* __restrict__ cnt, const int* __restrict__ bucket,
                              const float* __restrict__ mc, const float* __restrict__ upd_b,
                              const float* __restrict__ h_in, float* __restrict__ h_out)
{
    int t = blockIdx.x * blockDim.x + threadIdx.x;
    if (t >= N_ATOMS * BATCH) return;
    int n = t >> 4, b = t & 15;
    int dg = cnt[n];
    int base = n * 48 + b * 3;
    float d0, d1, d2;
    if (dg > 0) {
        int m = dg > BK ? BK : dg;
        float s0 = 0.f, s1 = 0.f, s2 = 0.f;
        const int* bk = bucket + n * BK;
        for (int j = 0; j < m; ++j) {
            const float* hs = h_in + bk[j] * 48 + b * 3;
            s0 += hs[0]; s1 += hs[1]; s2 += hs[2];
        }
        float inv = 1.f / (float)dg;
        s0 *= inv; s1 *= inv; s2 *= inv;
        d0 = mc[9]  + mc[0]*s0 + mc[1]*s1 + mc[2]*s2;
        d1 = mc[10] + mc[3]*s0 + mc[4]*s1 + mc[5]*s2;
        d2 = mc[11] + mc[6]*s0 + mc[7]*s1 + mc[8]*s2;
    } else {
        d0 = upd_b[0]; d1 = upd_b[1]; d2 = upd_b[2];
    }
    h_out[base]     = h_in[base]     + d0;
    h_out[base + 1] = h_in[base + 1] + d1;
    h_out[base + 2] = h_in[base + 2] + d2;
}

// ---------------- K5: MFMA output GEMM + b_out + go-affine(h) ----------------
// C[16 batch, 150000 rows] = X[16,256] @ W^T via mfma_f32_16x16x32_bf16.
// fp32 -> bf16 conversion IN REGISTERS (traffic stays 154MB; fp32 accum).
// A-frag: m = lane&15 = batch; B-frag: n = lane&15 = w row; both use the
// same consecutive-8 k scheme (k-permutation invariance).
// C/D (m89): r = tile*16 + (lane&15), batch = (lane>>4)*4 + reg.
// R15 change: 2 tiles/wave (was 4) -> 4688 waves = 18.3 waves/CU requested
// (~16 resident at ~128 VGPR) -> ~2x outstanding loads per CU vs R14's 9.2.
__global__ __launch_bounds__(256) void out_kernel(
    const float* __restrict__ w_out, const float* __restrict__ b_out,
    const float* __restrict__ x, const float* __restrict__ h_t,
    const float* __restrict__ go_w, const float* __restrict__ go_b,
    float* __restrict__ out)
{
    const int lane = threadIdx.x & 63;
    const int widx = threadIdx.x >> 6;
    const int wave = blockIdx.x * 4 + widx;   // 0..4687
    const int g  = lane >> 4;                 // k-group 0..3
    const int mn = lane & 15;                 // m(batch) for A, n(row) for B

    // A fragments once per wave: x[mn][kb*32 + g*8 + 0..7] as bf16x8
    bf16x8 afrag[8];
    const float* xrow = x + mn * 256 + g * 8;
    #pragma unroll
    for (int kb = 0; kb < 8; ++kb) {
        float4 lo = *reinterpret_cast<const float4*>(xrow + kb * 32);
        float4 hi = *reinterpret_cast<const float4*>(xrow + kb * 32 + 4);
        bf16x8 a;
        a[0] = (__bf16)lo.x; a[1] = (__bf16)lo.y; a[2] = (__bf16)lo.z; a[3] = (__bf16)lo.w;
        a[4] = (__bf16)hi.x; a[5] = (__bf16)hi.y; a[6] = (__bf16)hi.z; a[7] = (__bf16)hi.w;
        afrag[kb] = a;
    }

    #pragma unroll 1
    for (int t = 0; t < 2; ++t) {
        const int tile = wave * 2 + t;        // 9375 tiles of 16 rows
        if (tile >= 9375) break;
        const int r = tile * 16 + mn;
        const float* wrow = w_out + (size_t)r * 256 + g * 8;

        f32x4 acc = {0.f, 0.f, 0.f, 0.f};
        #pragma unroll
        for (int kb = 0; kb < 8; ++kb) {
            float4 lo = *reinterpret_cast<const float4*>(wrow + kb * 32);
            float4 hi = *reinterpret_cast<const float4*>(wrow + kb * 32 + 4);
            bf16x8 bfr;
            bfr[0] = (__bf16)lo.x; bfr[1] = (__bf16)lo.y; bfr[2] = (__bf16)lo.z; bfr[3] = (__bf16)lo.w;
            bfr[4] = (__bf16)hi.x; bfr[5] = (__bf16)hi.y; bfr[6] = (__bf16)hi.z; bfr[7] = (__bf16)hi.w;
            acc = __builtin_amdgcn_mfma_f32_16x16x32_bf16(afrag[kb], bfr, acc, 0, 0, 0);
        }

        const int n = r / 3, d = r - 3 * n;
        const float g0 = go_w[d*3], g1 = go_w[d*3 + 1], g2 = go_w[d*3 + 2];
        const float gb = go_b[d] + b_out[r];
        #pragma unroll
        for (int j = 0; j < 4; ++j) {
            const int b = g * 4 + j;          // batch = (lane>>4)*4 + reg
            const float* hb = h_t + n * 48 + b * 3;
            float gaff = gb + g0 * hb[0] + g1 * hb[1] + g2 * hb[2];
            out[(size_t)b * N3 + r] = acc[j] + gaff;
        }
    }
}

// ================= fallback (small-ws) kernels: atomic scatter path =================
__global__ void zero4_kernel(int4* __restrict__ p, int n4)
{
    int t = blockIdx.x * 256 + threadIdx.x;
    if (t < n4) p[t] = make_int4(0, 0, 0, 0);
}

__global__ void mlp_head_kernel(const float* __restrict__ alpha,
    const float* __restrict__ w_in, const float* __restrict__ b_in,
    const float* __restrict__ w1a, const float* __restrict__ b1a,
    const float* __restrict__ w1b, const float* __restrict__ b1b,
    const float* __restrict__ w2a, const float* __restrict__ b2a,
    const float* __restrict__ w2b, const float* __restrict__ b2b,
    const float* __restrict__ msg_w, const float* __restrict__ msg_b,
    const float* __restrict__ upd_w, const float* __restrict__ upd_b,
    float* __restrict__ x_out, float* __restrict__ mc)
{
    const int b = blockIdx.x, j = threadIdx.x;
    if (b == 16) {
        if (j < 9) {
            int d = j / 3, dp = j % 3;
            float s = 0.f;
            for (int k = 0; k < 128; ++k) s += upd_w[d*128 + k] * msg_w[k*3 + dp];
            mc[j] = s;
        } else if (j < 12) {
            int d = j - 9;
            float s = upd_b[d];
            for (int k = 0; k < 128; ++k) s += upd_w[d*128 + k] * msg_b[k];
            mc[9 + d] = s;
        }
        return;
    }
    __shared__ float xs[256];
    __shared__ float ts[256];
    mlp_block(b, j, alpha, w_in, b_in, w1a, b1a, w1b, b1b, w2a, b2a, w2b, b2b,
              xs, ts, x_out);
}

__global__ void transpose_in_kernel(const float* __restrict__ pos, float* __restrict__ h_t)
{
    int t = blockIdx.x * blockDim.x + threadIdx.x;
    if (t >= N_ATOMS * 48) return;
    int n = t / 48, c = t % 48;
    int b = c / 3, d = c % 3;
    h_t[t] = pos[(b * N_ATOMS + n) * 3 + d];
}

__global__ void degf_kernel(const int* __restrict__ bonds, float* __restrict__ deg)
{
    int e = blockIdx.x * blockDim.x + threadIdx.x;
    if (e >= N_BONDS) return;
    atomicAdd(deg + bonds[2*e],     1.f);
    atomicAdd(deg + bonds[2*e + 1], 1.f);
}

__global__ void scatter_kernel(const int* __restrict__ bonds,
                               const float* __restrict__ h_t, float* __restrict__ nb_t)
{
    int t = blockIdx.x * 192 + threadIdx.x;
    int e = t / 48, c = t % 48;
    if (e >= N_BONDS) return;
    int a  = bonds[2*e];
    int bb = bonds[2*e + 1];
    float va = h_t[a  * 48 + c];
    float vb = h_t[bb * 48 + c];
    atomicAdd(nb_t + bb * 48 + c, va);
    atomicAdd(nb_t + a  * 48 + c, vb);
}

__global__ void update_kernel(const float* __restrict__ nb_t, const float* __restrict__ deg,
                              const float* __restrict__ mc, const float* __restrict__ upd_b,
                              float* __restrict__ h_t)
{
    int t = blockIdx.x * blockDim.x + threadIdx.x;
    if (t >= N_ATOMS * BATCH) return;
    int n = t >> 4;
    int base = n * 48 + (t & 15) * 3;
    float dg = deg[n];
    float d0, d1, d2;
    if (dg > 0.f) {
        float inv = 1.f / dg;
        float m0 = nb_t[base] * inv, m1 = nb_t[base+1] * inv, m2 = nb_t[base+2] * inv;
        d0 = mc[9]  + mc[0]*m0 + mc[1]*m1 + mc[2]*m2;
        d1 = mc[10] + mc[3]*m0 + mc[4]*m1 + mc[5]*m2;
        d2 = mc[11] + mc[6]*m0 + mc[7]*m1 + mc[8]*m2;
    } else {
        d0 = upd_b[0]; d1 = upd_b[1]; d2 = upd_b[2];
    }
    h_t[base]     += d0;
    h_t[base + 1] += d1;
    h_t[base + 2] += d2;
}

extern "C" void kernel_launch(void* const* d_in, const int* in_sizes, int n_in,
                              void* d_out, int out_size, void* d_ws, size_t ws_size,
                              hipStream_t stream)
{
    const float* alpha = (const float*)d_in[0];
    const float* pos   = (const float*)d_in[1];
    const int*   bonds = (const int*)  d_in[2];
    const float* w_in  = (const float*)d_in[3];
    const float* b_in  = (const float*)d_in[4];
    const float* w1a   = (const float*)d_in[5];
    const float* b1a   = (const float*)d_in[6];
    const float* w1b   = (const float*)d_in[7];
    const float* b1b   = (const float*)d_in[8];
    const float* w2a   = (const float*)d_in[9];
    const float* b2a   = (const float*)d_in[10];
    const float* w2b   = (const float*)d_in[11];
    const float* b2b   = (const float*)d_in[12];
    const float* w_out = (const float*)d_in[13];
    const float* b_out = (const float*)d_in[14];
    const float* msg_w = (const float*)d_in[15];
    const float* msg_b = (const float*)d_in[16];
    const float* upd_w = (const float*)d_in[17];
    const float* upd_b = (const float*)d_in[18];
    const float* go_w  = (const float*)d_in[19];
    const float* go_b  = (const float*)d_in[20];

    float* out = (float*)d_out;
    float* ws  = (float*)d_ws;
    float* x   = ws + X_OFF;
    float* mc  = ws + MC_OFF;

    float* h_final;
    if (ws_size >= WS_FAST_BYTES) {
        // -------- 5-dispatch full-occupancy fast path --------
        PrepParams pp;
        pp.alpha = alpha; pp.pos = pos;
        pp.w_in = w_in; pp.b_in = b_in;
        pp.w1a = w1a; pp.b1a = b1a; pp.w1b = w1b; pp.b1b = b1b;
        pp.w2a = w2a; pp.b2a = b2a; pp.w2b = w2b; pp.b2b = b2b;
        pp.msg_w = msg_w; pp.msg_b = msg_b; pp.upd_w = upd_w; pp.upd_b = upd_b;
        pp.x = x; pp.mc = mc;
        pp.cnt = (int*)(ws + CNT_OFF);
        pp.hA  = ws + HA_OFF;
        prep_kernel<<<1024, 256, 0, stream>>>(pp);

        int* cnt    = (int*)(ws + CNT_OFF);
        int* bucket = (int*)(ws + BKT_OFF);
        float* hA   = ws + HA_OFF;
        float* hB   = ws + HB_OFF;

        fill_kernel<<<(N_BONDS + 255) / 256, 256, 0, stream>>>(bonds, cnt, bucket);
        gather_kernel<<<(N_ATOMS * BATCH + 255) / 256, 256, 0, stream>>>(cnt, bucket, mc, upd_b, hA, hB);
        gather_kernel<<<(N_ATOMS * BATCH + 255) / 256, 256, 0, stream>>>(cnt, bucket, mc, upd_b, hB, hA);
        h_final = hA;
    } else {
        // -------- fallback: multi-dispatch atomic scatter path --------
        float* degf = ws + DEGF_OFF;
        float* h_t  = ws + HT_OFF;
        size_t need_full = (size_t)(NB_OFF + N_ATOMS * 48) * sizeof(float);
        float* nb_t = (ws_size >= need_full) ? (ws + NB_OFF) : out;

        mlp_head_kernel<<<17, 256, 0, stream>>>(alpha, w_in, b_in,
                                                w1a, b1a, w1b, b1b,
                                                w2a, b2a, w2b, b2b,
                                                msg_w, msg_b, upd_w, upd_b, x, mc);
        zero4_kernel<<<(N_ATOMS / 4 + 255) / 256, 256, 0, stream>>>((int4*)degf, N_ATOMS / 4);
        degf_kernel<<<(N_BONDS + 255) / 256, 256, 0, stream>>>(bonds, degf);
        transpose_in_kernel<<<(N_ATOMS * 48 + 255) / 256, 256, 0, stream>>>(pos, h_t);
        for (int it = 0; it < 2; ++it) {
            zero4_kernel<<<(N_ATOMS * 48 / 4 + 255) / 256, 256, 0, stream>>>((int4*)nb_t, N_ATOMS * 48 / 4);
            scatter_kernel<<<25000, 192, 0, stream>>>(bonds, h_t, nb_t);
            update_kernel<<<(N_ATOMS * BATCH + 255) / 256, 256, 0, stream>>>(nb_t, degf, mc, upd_b, h_t);
        }
        h_final = h_t;
    }

    // MFMA GEMM: 1172 blocks x 4 waves, 2 tiles (32 rows) per wave
    out_kernel<<<1172, 256, 0, stream>>>(w_out, b_out, x, h_final, go_w, go_b, out);
}

// Round 16
// 112.821 us; speedup vs baseline: 1.0387x; 1.0387x over previous
//
#include <hip/hip_runtime.h>

#define N_ATOMS 50000
#define N_BONDS 100000
#define BATCH   16
#define N3      150000   // N_ATOMS*3
#define BK      32       // bucket capacity per atom (Poisson(4): P(deg>32) ~ 1e-15)
#define NTILES  9375     // N3/16 rows per MFMA tile

// ---- fast-path workspace layout (4-byte element offsets) ----
#define X_OFF    0            // 4096 floats
#define MC_OFF   4096         // 16 floats (M 9, c 3)
#define CNT_OFF  4112         // 50000 ints
#define BKT_OFF  54112        // 50000*32 = 1,600,000 ints
#define HA_OFF   1654112      // 2,400,000 floats
#define HB_OFF   4054112      // 2,400,000 floats
#define WS_FAST_BYTES ((size_t)(HB_OFF + 2400000) * 4)   // ~25.8 MB

// ---- fallback layout ----
#define DEGF_OFF 4112         // 50000 floats
#define HT_OFF   54144        // 2,400,000 floats
#define NB_OFF   2454144      // 2,400,000 floats (optional in ws)

typedef __bf16 bf16x8 __attribute__((ext_vector_type(8)));
typedef float  f32x4  __attribute__((ext_vector_type(4)));

// ================= shared device helpers =================

// tiny MLP for batch b; all 256 threads of the block participate.
__device__ __forceinline__ void mlp_block(int b, int j,
    const float* __restrict__ alpha,
    const float* __restrict__ w_in, const float* __restrict__ b_in,
    const float* __restrict__ w1a, const float* __restrict__ b1a,
    const float* __restrict__ w1b, const float* __restrict__ b1b,
    const float* __restrict__ w2a, const float* __restrict__ b2a,
    const float* __restrict__ w2b, const float* __restrict__ b2b,
    float* xs, float* ts, float* __restrict__ x_out)
{
    float v = fmaxf(w_in[j] * alpha[b] + b_in[j], 0.f);
    xs[j] = v;
    __syncthreads();

    float acc = b1a[j];
    const float4* wr = reinterpret_cast<const float4*>(w1a + j * 256);
    #pragma unroll 8
    for (int k4 = 0; k4 < 64; ++k4) {
        float4 w = wr[k4];
        acc += w.x * xs[4*k4] + w.y * xs[4*k4+1] + w.z * xs[4*k4+2] + w.w * xs[4*k4+3];
    }
    ts[j] = fmaxf(acc, 0.f);
    __syncthreads();

    acc = b1b[j] + xs[j];
    wr = reinterpret_cast<const float4*>(w1b + j * 256);
    #pragma unroll 8
    for (int k4 = 0; k4 < 64; ++k4) {
        float4 w = wr[k4];
        acc += w.x * ts[4*k4] + w.y * ts[4*k4+1] + w.z * ts[4*k4+2] + w.w * ts[4*k4+3];
    }
    v = fmaxf(acc, 0.f);
    __syncthreads();
    xs[j] = v;
    __syncthreads();

    acc = b2a[j];
    wr = reinterpret_cast<const float4*>(w2a + j * 256);
    #pragma unroll 8
    for (int k4 = 0; k4 < 64; ++k4) {
        float4 w = wr[k4];
        acc += w.x * xs[4*k4] + w.y * xs[4*k4+1] + w.z * xs[4*k4+2] + w.w * xs[4*k4+3];
    }
    ts[j] = fmaxf(acc, 0.f);
    __syncthreads();

    acc = b2b[j] + xs[j];
    wr = reinterpret_cast<const float4*>(w2b + j * 256);
    #pragma unroll 8
    for (int k4 = 0; k4 < 64; ++k4) {
        float4 w = wr[k4];
        acc += w.x * ts[4*k4] + w.y * ts[4*k4+1] + w.z * ts[4*k4+2] + w.w * ts[4*k4+3];
    }
    x_out[b * 256 + j] = fmaxf(acc, 0.f);
}

// ================= K1: prep (MLP + mc + transpose + cnt-zero) =================
// Transpose keeps R7's proven mapping: coalesced WRITES to h, 12B scattered
// reads of pos (L2-absorbed). R8's read-coalesced variant regressed 15-20us.
struct PrepParams {
    const float *alpha, *pos;
    const float *w_in, *b_in, *w1a, *b1a, *w1b, *b1b, *w2a, *b2a, *w2b, *b2b;
    const float *msg_w, *msg_b, *upd_w, *upd_b;
    float *x, *mc;
    int *cnt;
    float *hA;
};

__global__ __launch_bounds__(256) void prep_kernel(PrepParams p)
{
    __shared__ float smem[512];
    const int bid = blockIdx.x, tid = threadIdx.x;
    const int nb = gridDim.x;

    if (bid < 16) {
        mlp_block(bid, tid, p.alpha, p.w_in, p.b_in,
                  p.w1a, p.b1a, p.w1b, p.b1b, p.w2a, p.b2a, p.w2b, p.b2b,
                  smem, smem + 256, p.x);
    } else if (bid == 16) {
        if (tid < 9) {
            int d = tid / 3, dp = tid % 3;
            float s = 0.f;
            for (int k = 0; k < 128; ++k) s += p.upd_w[d*128 + k] * p.msg_w[k*3 + dp];
            p.mc[tid] = s;
        } else if (tid < 12) {
            int d = tid - 9;
            float s = p.upd_b[d];
            for (int k = 0; k < 128; ++k) s += p.upd_w[d*128 + k] * p.msg_b[k];
            p.mc[9 + d] = s;
        }
    } else {
        const int i0 = (bid - 17) * 256 + tid;
        const int st = (nb - 17) * 256;
        if (i0 < N_ATOMS / 4)
            ((int4*)p.cnt)[i0] = make_int4(0, 0, 0, 0);
        for (int i = i0; i < N_ATOMS * 48; i += st) {
            int n = i / 48, c = i - n * 48;
            int b = c / 3, d = c - b * 3;
            p.hA[i] = p.pos[(b * N_ATOMS + n) * 3 + d];
        }
    }
}

// ================= K2: bucket fill (count + adjacency in one pass) =================
__global__ void fill_kernel(const int* __restrict__ bonds, int* __restrict__ cnt,
                            int* __restrict__ bucket)
{
    int e = blockIdx.x * blockDim.x + threadIdx.x;
    if (e >= N_BONDS) return;
    int a = bonds[2*e], b = bonds[2*e + 1];
    int sa = atomicAdd(cnt + a, 1);
    if (sa < BK) bucket[a * BK + sa] = b;
    int sb = atomicAdd(cnt + b, 1);
    if (sb < BK) bucket[b * BK + sb] = a;
}

// ============ K3/K4: bucket gather + mean + affine + residual ============
__global__ void gather_kernel(const int* __restrict__ cnt, const int* __restrict__ bucket,
                              const float* __restrict__ mc, const float* __restrict__ upd_b,
                              const float* __restrict__ h_in, float* __restrict__ h_out)
{
    int t = blockIdx.x * blockDim.x + threadIdx.x;
    if (t >= N_ATOMS * BATCH) return;
    int n = t >> 4, b = t & 15;
    int dg = cnt[n];
    int base = n * 48 + b * 3;
    float d0, d1, d2;
    if (dg > 0) {
        int m = dg > BK ? BK : dg;
        float s0 = 0.f, s1 = 0.f, s2 = 0.f;
        const int* bk = bucket + n * BK;
        for (int j = 0; j < m; ++j) {
            const float* hs = h_in + bk[j] * 48 + b * 3;
            s0 += hs[0]; s1 += hs[1]; s2 += hs[2];
        }
        float inv = 1.f / (float)dg;
        s0 *= inv; s1 *= inv; s2 *= inv;
        d0 = mc[9]  + mc[0]*s0 + mc[1]*s1 + mc[2]*s2;
        d1 = mc[10] + mc[3]*s0 + mc[4]*s1 + mc[5]*s2;
        d2 = mc[11] + mc[6]*s0 + mc[7]*s1 + mc[8]*s2;
    } else {
        d0 = upd_b[0]; d1 = upd_b[1]; d2 = upd_b[2];
    }
    h_out[base]     = h_in[base]     + d0;
    h_out[base + 1] = h_in[base + 1] + d1;
    h_out[base + 2] = h_in[base + 2] + d2;
}

// ---------------- K5: MFMA output GEMM, LDS-staged via global_load_lds ----------------
// Change vs R15: w tile (16 rows x 1KB, CONTIGUOUS 16KB) is DMA'd to LDS with
// 16 global_load_lds dwordx4 ops -> each VMEM instruction requests 1KB fully
// contiguous (wave-uniform LDS base + lane*16B), replacing the 16-row
// scattered lattice that pinned the stream at ~2.1 TB/s (R14==R15 null).
// Double-buffered; s_waitcnt vmcnt(16) = wait oldest 16 (current buf) while
// next tile's 16 DMAs fly (m135 in-order semantics; younger epilogue stores
// don't matter). LDS row stride 268 floats (1072B): consecutive-lane ds_read
// banks stride 12 -> only mn/mn+8 2-way aliasing (free, m136).
// Numerics identical to R15 (same k-map, same order) -> absmax 0.0625.
__global__ __launch_bounds__(64) void out_kernel(
    const float* __restrict__ w_out, const float* __restrict__ b_out,
    const float* __restrict__ x, const float* __restrict__ h_t,
    const float* __restrict__ go_w, const float* __restrict__ go_b,
    float* __restrict__ out)
{
    __shared__ float lds[2][16][268];           // 34,304 B -> 4 blocks/CU
    const int lane = threadIdx.x;               // 0..63 (one wave per block)
    const int g  = lane >> 4;                   // k-group 0..3
    const int mn = lane & 15;                   // m(batch) for A, n(row) for B

    // A fragments once per wave: x[mn][kb*32 + g*8 + 0..7] as bf16x8
    bf16x8 afrag[8];
    const float* xrow = x + mn * 256 + g * 8;
    #pragma unroll
    for (int kb = 0; kb < 8; ++kb) {
        float4 lo = *reinterpret_cast<const float4*>(xrow + kb * 32);
        float4 hi = *reinterpret_cast<const float4*>(xrow + kb * 32 + 4);
        bf16x8 a;
        a[0] = (__bf16)lo.x; a[1] = (__bf16)lo.y; a[2] = (__bf16)lo.z; a[3] = (__bf16)lo.w;
        a[4] = (__bf16)hi.x; a[5] = (__bf16)hi.y; a[6] = (__bf16)hi.z; a[7] = (__bf16)hi.w;
        afrag[kb] = a;
    }

    const int t0 = blockIdx.x * 4;

    // stage one 16-row tile: 16 x (1KB contiguous, lane*16B) -> LDS rows @268f
    auto stage16 = [&](int tile, int buf) {
        const float* gsrc = w_out + (size_t)tile * 16 * 256;
        #pragma unroll
        for (int i = 0; i < 16; ++i) {
            __builtin_amdgcn_global_load_lds(
                (const __attribute__((address_space(1))) unsigned int*)(gsrc + i * 256 + lane * 4),
                (__attribute__((address_space(3))) unsigned int*)(&lds[buf][i][0]),
                16, 0, 0);
        }
    };

    if (t0 < NTILES) stage16(t0, 0);

    #pragma unroll 1
    for (int t = 0; t < 4; ++t) {
        const int tile = t0 + t;
        if (tile >= NTILES) break;
        const bool nxt = (t + 1 < 4) && (tile + 1 < NTILES);
        if (nxt) {
            stage16(tile + 1, (t + 1) & 1);
            asm volatile("s_waitcnt vmcnt(16)" ::: "memory");
        } else {
            asm volatile("s_waitcnt vmcnt(0)" ::: "memory");
        }
        __builtin_amdgcn_sched_barrier(0);

        const float* lrow = &lds[t & 1][mn][0];
        f32x4 acc = {0.f, 0.f, 0.f, 0.f};
        #pragma unroll
        for (int kb = 0; kb < 8; ++kb) {
            float4 lo = *reinterpret_cast<const float4*>(lrow + kb * 32 + g * 8);
            float4 hi = *reinterpret_cast<const float4*>(lrow + kb * 32 + g * 8 + 4);
            bf16x8 bfr;
            bfr[0] = (__bf16)lo.x; bfr[1] = (__bf16)lo.y; bfr[2] = (__bf16)lo.z; bfr[3] = (__bf16)lo.w;
            bfr[4] = (__bf16)hi.x; bfr[5] = (__bf16)hi.y; bfr[6] = (__bf16)hi.z; bfr[7] = (__bf16)hi.w;
            acc = __builtin_amdgcn_mfma_f32_16x16x32_bf16(afrag[kb], bfr, acc, 0, 0, 0);
        }

        const int r = tile * 16 + mn;
        const int n = r / 3, d = r - 3 * n;
        const float g0 = go_w[d*3], g1 = go_w[d*3 + 1], g2 = go_w[d*3 + 2];
        const float gb = go_b[d] + b_out[r];
        #pragma unroll
        for (int j = 0; j < 4; ++j) {
            const int b = g * 4 + j;          // batch = (lane>>4)*4 + reg
            const float* hb = h_t + n * 48 + b * 3;
            float gaff = gb + g0 * hb[0] + g1 * hb[1] + g2 * hb[2];
            out[(size_t)b * N3 + r] = acc[j] + gaff;
        }
    }
}

// ================= fallback (small-ws) kernels: atomic scatter path =================
__global__ void zero4_kernel(int4* __restrict__ p, int n4)
{
    int t = blockIdx.x * 256 + threadIdx.x;
    if (t < n4) p[t] = make_int4(0, 0, 0, 0);
}

__global__ void mlp_head_kernel(const float* __restrict__ alpha,
    const float* __restrict__ w_in, const float* __restrict__ b_in,
    const float* __restrict__ w1a, const float* __restrict__ b1a,
    const float* __restrict__ w1b, const float* __restrict__ b1b,
    const float* __restrict__ w2a, const float* __restrict__ b2a,
    const float* __restrict__ w2b, const float* __restrict__ b2b,
    const float* __restrict__ msg_w, const float* __restrict__ msg_b,
    const float* __restrict__ upd_w, const float* __restrict__ upd_b,
    float* __restrict__ x_out, float* __restrict__ mc)
{
    const int b = blockIdx.x, j = threadIdx.x;
    if (b == 16) {
        if (j < 9) {
            int d = j / 3, dp = j % 3;
            float s = 0.f;
            for (int k = 0; k < 128; ++k) s += upd_w[d*128 + k] * msg_w[k*3 + dp];
            mc[j] = s;
        } else if (j < 12) {
            int d = j - 9;
            float s = upd_b[d];
            for (int k = 0; k < 128; ++k) s += upd_w[d*128 + k] * msg_b[k];
            mc[9 + d] = s;
        }
        return;
    }
    __shared__ float xs[256];
    __shared__ float ts[256];
    mlp_block(b, j, alpha, w_in, b_in, w1a, b1a, w1b, b1b, w2a, b2a, w2b, b2b,
              xs, ts, x_out);
}

__global__ void transpose_in_kernel(const float* __restrict__ pos, float* __restrict__ h_t)
{
    int t = blockIdx.x * blockDim.x + threadIdx.x;
    if (t >= N_ATOMS * 48) return;
    int n = t / 48, c = t % 48;
    int b = c / 3, d = c % 3;
    h_t[t] = pos[(b * N_ATOMS + n) * 3 + d];
}

__global__ void degf_kernel(const int* __restrict__ bonds, float* __restrict__ deg)
{
    int e = blockIdx.x * blockDim.x + threadIdx.x;
    if (e >= N_BONDS) return;
    atomicAdd(deg + bonds[2*e],     1.f);
    atomicAdd(deg + bonds[2*e + 1], 1.f);
}

__global__ void scatter_kernel(const int* __restrict__ bonds,
                               const float* __restrict__ h_t, float* __restrict__ nb_t)
{
    int t = blockIdx.x * 192 + threadIdx.x;
    int e = t / 48, c = t % 48;
    if (e >= N_BONDS) return;
    int a  = bonds[2*e];
    int bb = bonds[2*e + 1];
    float va = h_t[a  * 48 + c];
    float vb = h_t[bb * 48 + c];
    atomicAdd(nb_t + bb * 48 + c, va);
    atomicAdd(nb_t + a  * 48 + c, vb);
}

__global__ void update_kernel(const float* __restrict__ nb_t, const float* __restrict__ deg,
                              const float* __restrict__ mc, const float* __restrict__ upd_b,
                              float* __restrict__ h_t)
{
    int t = blockIdx.x * blockDim.x + threadIdx.x;
    if (t >= N_ATOMS * BATCH) return;
    int n = t >> 4;
    int base = n * 48 + (t & 15) * 3;
    float dg = deg[n];
    float d0, d1, d2;
    if (dg > 0.f) {
        float inv = 1.f / dg;
        float m0 = nb_t[base] * inv, m1 = nb_t[base+1] * inv, m2 = nb_t[base+2] * inv;
        d0 = mc[9]  + mc[0]*m0 + mc[1]*m1 + mc[2]*m2;
        d1 = mc[10] + mc[3]*m0 + mc[4]*m1 + mc[5]*m2;
        d2 = mc[11] + mc[6]*m0 + mc[7]*m1 + mc[8]*m2;
    } else {
        d0 = upd_b[0]; d1 = upd_b[1]; d2 = upd_b[2];
    }
    h_t[base]     += d0;
    h_t[base + 1] += d1;
    h_t[base + 2] += d2;
}

extern "C" void kernel_launch(void* const* d_in, const int* in_sizes, int n_in,
                              void* d_out, int out_size, void* d_ws, size_t ws_size,
                              hipStream_t stream)
{
    const float* alpha = (const float*)d_in[0];
    const float* pos   = (const float*)d_in[1];
    const int*   bonds = (const int*)  d_in[2];
    const float* w_in  = (const float*)d_in[3];
    const float* b_in  = (const float*)d_in[4];
    const float* w1a   = (const float*)d_in[5];
    const float* b1a   = (const float*)d_in[6];
    const float* w1b   = (const float*)d_in[7];
    const float* b1b   = (const float*)d_in[8];
    const float* w2a   = (const float*)d_in[9];
    const float* b2a   = (const float*)d_in[10];
    const float* w2b   = (const float*)d_in[11];
    const float* b2b   = (const float*)d_in[12];
    const float* w_out = (const float*)d_in[13];
    const float* b_out = (const float*)d_in[14];
    const float* msg_w = (const float*)d_in[15];
    const float* msg_b = (const float*)d_in[16];
    const float* upd_w = (const float*)d_in[17];
    const float* upd_b = (const float*)d_in[18];
    const float* go_w  = (const float*)d_in[19];
    const float* go_b  = (const float*)d_in[20];

    float* out = (float*)d_out;
    float* ws  = (float*)d_ws;
    float* x   = ws + X_OFF;
    float* mc  = ws + MC_OFF;

    float* h_final;
    if (ws_size >= WS_FAST_BYTES) {
        // -------- 5-dispatch full-occupancy fast path --------
        PrepParams pp;
        pp.alpha = alpha; pp.pos = pos;
        pp.w_in = w_in; pp.b_in = b_in;
        pp.w1a = w1a; pp.b1a = b1a; pp.w1b = w1b; pp.b1b = b1b;
        pp.w2a = w2a; pp.b2a = b2a; pp.w2b = w2b; pp.b2b = b2b;
        pp.msg_w = msg_w; pp.msg_b = msg_b; pp.upd_w = upd_w; pp.upd_b = upd_b;
        pp.x = x; pp.mc = mc;
        pp.cnt = (int*)(ws + CNT_OFF);
        pp.hA  = ws + HA_OFF;
        prep_kernel<<<1024, 256, 0, stream>>>(pp);

        int* cnt    = (int*)(ws + CNT_OFF);
        int* bucket = (int*)(ws + BKT_OFF);
        float* hA   = ws + HA_OFF;
        float* hB   = ws + HB_OFF;

        fill_kernel<<<(N_BONDS + 255) / 256, 256, 0, stream>>>(bonds, cnt, bucket);
        gather_kernel<<<(N_ATOMS * BATCH + 255) / 256, 256, 0, stream>>>(cnt, bucket, mc, upd_b, hA, hB);
        gather_kernel<<<(N_ATOMS * BATCH + 255) / 256, 256, 0, stream>>>(cnt, bucket, mc, upd_b, hB, hA);
        h_final = hA;
    } else {
        // -------- fallback: multi-dispatch atomic scatter path --------
        float* degf = ws + DEGF_OFF;
        float* h_t  = ws + HT_OFF;
        size_t need_full = (size_t)(NB_OFF + N_ATOMS * 48) * sizeof(float);
        float* nb_t = (ws_size >= need_full) ? (ws + NB_OFF) : out;

        mlp_head_kernel<<<17, 256, 0, stream>>>(alpha, w_in, b_in,
                                                w1a, b1a, w1b, b1b,
                                                w2a, b2a, w2b, b2b,
                                                msg_w, msg_b, upd_w, upd_b, x, mc);
        zero4_kernel<<<(N_ATOMS / 4 + 255) / 256, 256, 0, stream>>>((int4*)degf, N_ATOMS / 4);
        degf_kernel<<<(N_BONDS + 255) / 256, 256, 0, stream>>>(bonds, degf);
        transpose_in_kernel<<<(N_ATOMS * 48 + 255) / 256, 256, 0, stream>>>(pos, h_t);
        for (int it = 0; it < 2; ++it) {
            zero4_kernel<<<(N_ATOMS * 48 / 4 + 255) / 256, 256, 0, stream>>>((int4*)nb_t, N_ATOMS * 48 / 4);
            scatter_kernel<<<25000, 192, 0, stream>>>(bonds, h_t, nb_t);
            update_kernel<<<(N_ATOMS * BATCH + 255) / 256, 256, 0, stream>>>(nb_t, degf, mc, upd_b, h_t);
        }
        h_final = h_t;
    }

    // MFMA GEMM, LDS-staged: 2344 blocks x 1 wave, 4 tiles per wave
    out_kernel<<<2344, 64, 0, stream>>>(w_out, b_out, x, h_final, go_w, go_b, out);
}